// Round 3
// baseline (1243.168 us; speedup 1.0000x reference)
//
#include <hip/hip_runtime.h>
#include <hip/hip_bf16.h>

typedef unsigned int u32;
typedef unsigned long long u64;

// ---------------- Threefry-2x32 (20 rounds), exact JAX semantics ----------------
__host__ __device__ __forceinline__ void tf2x32(u32 k0, u32 k1, u32 x0, u32 x1,
                                                u32& o0, u32& o1)
{
    const u32 ks2 = k0 ^ k1 ^ 0x1BD11BDAu;
    x0 += k0; x1 += k1;
#define TF_R(r) { x0 += x1; x1 = (x1 << (r)) | (x1 >> (32 - (r))); x1 ^= x0; }
    TF_R(13) TF_R(15) TF_R(26) TF_R(6)
    x0 += k1; x1 += ks2 + 1u;
    TF_R(17) TF_R(29) TF_R(16) TF_R(24)
    x0 += ks2; x1 += k0 + 2u;
    TF_R(13) TF_R(15) TF_R(26) TF_R(6)
    x0 += k0; x1 += k1 + 3u;
    TF_R(17) TF_R(29) TF_R(16) TF_R(24)
    x0 += k1; x1 += ks2 + 4u;
    TF_R(13) TF_R(15) TF_R(26) TF_R(6)
    x0 += ks2; x1 += k0 + 5u;
#undef TF_R
    o0 = x0; o1 = x1;
}

// partitionable random_bits: counter = (hi=0, lo=e), bits = o0 ^ o1
__device__ __forceinline__ u32 rbits(u32 k0, u32 k1, u32 e)
{
    u32 o0, o1; tf2x32(k0, k1, 0u, e, o0, o1); return o0 ^ o1;
}

#define HW        262144u      // 512*512 = 2^18
#define KEEP      183500u      // int(262144*0.7)
#define NX        50331648u    // 64*3*512*512
#define NM        16777216u    // 64*512*512
#define WLO       2835u        // window around 0.7-quantile coarse bin 2867 (+-32 = 8.7 sigma)
#define NWIN      65u
#define CAP       8192u        // global candidate capacity per row (mean 4160, 60+ sigma)
#define LCAP      1024u        // in-bin LDS candidate capacity (mean 64, 120 sigma)
#define LO_F      (-0.99999994039535522461f)   // -(1-2^-24)

__device__ __forceinline__ float noise_from_bits(u32 bits)
{
    float f  = __uint_as_float((bits >> 9) | 0x3F800000u) - 1.0f;   // [0,1)
    float un = fmaf(f, 2.0f, LO_F);
    un = fmaxf(LO_F, un);
    // Giles single-precision erfinv (XLA-style)
    float w = -__logf(fmaf(-un, un, 1.0f));
    float p;
    if (w < 5.0f) {
        w -= 2.5f;
        p = 2.81022636e-08f;
        p = fmaf(p, w, 3.43273939e-07f);
        p = fmaf(p, w, -3.5233877e-06f);
        p = fmaf(p, w, -4.39150654e-06f);
        p = fmaf(p, w, 0.00021858087f);
        p = fmaf(p, w, -0.00125372503f);
        p = fmaf(p, w, -0.00417768164f);
        p = fmaf(p, w, 0.246640727f);
        p = fmaf(p, w, 1.50140941f);
    } else {
        w = __fsqrt_rn(w) - 3.0f;
        p = -0.000200214257f;
        p = fmaf(p, w, 0.000100950558f);
        p = fmaf(p, w, 0.00134934322f);
        p = fmaf(p, w, -0.00367342844f);
        p = fmaf(p, w, 0.00573950773f);
        p = fmaf(p, w, -0.0076224613f);
        p = fmaf(p, w, 0.00943887047f);
        p = fmaf(p, w, 1.00167406f);
        p = fmaf(p, w, 2.83297682f);
    }
    float ei = p * un;
    return fmaf(1.41421356f * ei, 0.1f, 1.0f);
}

// kA: regenerate mask ciphers; per row accumulate below-window count, windowed
// 65-bin hist, and append in-window candidates ((m<<18)|p packed u64).
// 1024 blocks x 256 thr; block covers 16384 consecutive pixels (16 blocks/row).
__global__ __launch_bounds__(256) void kA_hist(u32 mk0, u32 mk1, u32* winhist,
                                               u32* candcnt, u64* cand)
{
    __shared__ u32 wh[NWIN];
    __shared__ u32 red[256];
    const int t = threadIdx.x;
    const u32 blk = blockIdx.x;
    const u32 row = blk >> 4;
    const u32 base = blk << 14;
    for (int i = t; i < (int)NWIN; i += 256) wh[i] = 0;
    __syncthreads();
    u32 below = 0;
#pragma unroll 1
    for (int i = 0; i < 16; ++i) {
        u32 vi = (u32)(i << 8) + (u32)t;
        u32 e = base + (vi << 2);
        u32 p = e & (HW - 1u);
        u32 m0 = rbits(mk0, mk1, e)      >> 9;
        u32 m1 = rbits(mk0, mk1, e + 1u) >> 9;
        u32 m2 = rbits(mk0, mk1, e + 2u) >> 9;
        u32 m3 = rbits(mk0, mk1, e + 3u) >> 9;
#define DO_EL(mm, pp) { u32 bin = (mm) >> 11; below += (bin < WLO) ? 1u : 0u;          \
        u32 wb = bin - WLO;                                                            \
        if (wb < NWIN) { atomicAdd(&wh[wb], 1u);                                       \
            u32 pos = atomicAdd(&candcnt[row], 1u);                                    \
            if (pos < CAP) cand[((u64)row << 13) + pos] = ((u64)(mm) << 18) | (u64)(pp); } }
        DO_EL(m0, p) DO_EL(m1, p + 1u) DO_EL(m2, p + 2u) DO_EL(m3, p + 3u)
#undef DO_EL
    }
    red[t] = below;
    __syncthreads();
    for (int s = 128; s > 0; s >>= 1) { if (t < s) red[t] += red[t + s]; __syncthreads(); }
    if (t == 0 && red[0]) atomicAdd(&winhist[row * 66u], red[0]);
    if (t < (int)NWIN) { u32 v = wh[t]; if (v) atomicAdd(&winhist[row * 66u + 1u + (u32)t], v); }
}

// kB: per-row exact threshold. Normal path: rank within windowed hist ->
// filter candidates in bin B -> exact rank-select. Fallback (B outside
// window / overflow, deterministic & ~never): full in-block regen.
__global__ __launch_bounds__(256) void kB_select(u32 mk0, u32 mk1,
                                                 const u32* winhist, const u32* candcnt,
                                                 const u64* cand, u64* rowsel)
{
    __shared__ u64 lc[LCAP];
    __shared__ u32 fh[4096];
    __shared__ u32 lcnt, sB, sr, sfb;
    const int t = threadIdx.x;       // 256
    const u32 row = blockIdx.x;      // 64
    if (t == 0) {
        u32 bl = winhist[row * 66u];
        u32 cum = bl, B = 0xFFFFFFFFu, r = 0;
        if (KEEP > bl) {
            for (u32 i = 0; i < NWIN; ++i) {
                u32 h = winhist[row * 66u + 1u + i];
                if (cum + h >= KEEP) { B = WLO + i; r = KEEP - cum; break; }
                cum += h;
            }
        }
        sfb = (B == 0xFFFFFFFFu || candcnt[row] > CAP) ? 1u : 0u;
        sB = B; sr = r; lcnt = 0;
    }
    __syncthreads();
    if (sfb) {
        // ---- fallback: exact full recompute for this row ----
        for (int i = t; i < 4096; i += 256) fh[i] = 0;
        __syncthreads();
        for (u32 i = (u32)t; i < 65536u; i += 256u) {
            u32 e = (row << 18) + (i << 2);
            u32 m0 = rbits(mk0, mk1, e) >> 9, m1 = rbits(mk0, mk1, e + 1u) >> 9;
            u32 m2 = rbits(mk0, mk1, e + 2u) >> 9, m3 = rbits(mk0, mk1, e + 3u) >> 9;
            atomicAdd(&fh[m0 >> 11], 1u); atomicAdd(&fh[m1 >> 11], 1u);
            atomicAdd(&fh[m2 >> 11], 1u); atomicAdd(&fh[m3 >> 11], 1u);
        }
        __syncthreads();
        if (t == 0) {
            u32 cum = 0;
            for (u32 i = 0; i < 4096u; ++i) {
                u32 h = fh[i];
                if (cum + h >= KEEP) { sB = i; sr = KEEP - cum; break; }
                cum += h;
            }
        }
        __syncthreads();
        for (u32 i = (u32)t; i < 65536u; i += 256u) {
            u32 e = (row << 18) + (i << 2);
            u32 p = i << 2;
            u32 mm[4];
            mm[0] = rbits(mk0, mk1, e) >> 9; mm[1] = rbits(mk0, mk1, e + 1u) >> 9;
            mm[2] = rbits(mk0, mk1, e + 2u) >> 9; mm[3] = rbits(mk0, mk1, e + 3u) >> 9;
#pragma unroll
            for (u32 j = 0; j < 4u; ++j)
                if ((mm[j] >> 11) == sB) {
                    u32 pos = atomicAdd(&lcnt, 1u);
                    if (pos < LCAP) lc[pos] = ((u64)mm[j] << 18) | (u64)(p + j);
                }
        }
    } else {
        u32 cnt = candcnt[row];
        for (u32 i = (u32)t; i < cnt; i += 256u) {
            u64 k = cand[((u64)row << 13) + i];
            if ((u32)(k >> 29) == sB) {
                u32 pos = atomicAdd(&lcnt, 1u);
                if (pos < LCAP) lc[pos] = k;
            }
        }
    }
    __syncthreads();
    u32 n = lcnt; if (n > LCAP) n = LCAP;
    u32 want = sr - 1u;
    for (u32 i = (u32)t; i < n; i += 256u) {
        u64 me = lc[i];
        u32 rk = 0;
        for (u32 j = 0; j < n; ++j) rk += (lc[j] < me) ? 1u : 0u;
        if (rk == want) rowsel[row] = me;
    }
}

// kC: fused regen-mask + noise + multiply. One thread owns pixel-quad for all
// 3 channels; writes 3 output quads + the float mask quad.
__global__ __launch_bounds__(256) void kC_fused(const float4* __restrict__ x4,
                                                float4* __restrict__ out4,
                                                float4* __restrict__ maskout,
                                                const u64* __restrict__ rowsel,
                                                u32 mk0, u32 mk1, u32 nk0, u32 nk1)
{
    u32 tid = blockIdx.x * 256u + threadIdx.x;    // 4194304 pixel-quads
    u32 b  = tid >> 16;
    u32 pq = tid & 65535u;
    u32 p  = pq << 2;
    u64 kst = rowsel[b];
    u32 em = (b << 18) + p;
    u32 q0 = rbits(mk0, mk1, em)      >> 9;
    u32 q1 = rbits(mk0, mk1, em + 1u) >> 9;
    u32 q2 = rbits(mk0, mk1, em + 2u) >> 9;
    u32 q3 = rbits(mk0, mk1, em + 3u) >> 9;
    float4 mk;
    mk.x = ((((u64)q0 << 18) | (u64)p)        <= kst) ? 1.0f : 0.0f;
    mk.y = ((((u64)q1 << 18) | (u64)(p + 1u)) <= kst) ? 1.0f : 0.0f;
    mk.z = ((((u64)q2 << 18) | (u64)(p + 2u)) <= kst) ? 1.0f : 0.0f;
    mk.w = ((((u64)q3 << 18) | (u64)(p + 3u)) <= kst) ? 1.0f : 0.0f;
#pragma unroll
    for (u32 ch = 0; ch < 3u; ++ch) {
        u32 xi = ((b * 3u + ch) << 16) + pq;
        u32 e  = ((b * 3u + ch) << 18) + p;
        float4 xv = x4[xi];
        float4 rr;
        rr.x = (xv.x * mk.x) * noise_from_bits(rbits(nk0, nk1, e));
        rr.y = (xv.y * mk.y) * noise_from_bits(rbits(nk0, nk1, e + 1u));
        rr.z = (xv.z * mk.z) * noise_from_bits(rbits(nk0, nk1, e + 2u));
        rr.w = (xv.w * mk.w) * noise_from_bits(rbits(nk0, nk1, e + 3u));
        out4[xi] = rr;
    }
    maskout[tid] = mk;
}

extern "C" void kernel_launch(void* const* d_in, const int* in_sizes, int n_in,
                              void* d_out, int out_size, void* d_ws, size_t ws_size,
                              hipStream_t stream) {
    const float* x = (const float*)d_in[0];
    float* xout = (float*)d_out;                  // 50331648 floats (x output)
    float* maskout = xout + NX;                   // 16777216 floats (mask output)

    u32* wsu = (u32*)d_ws;
    u32* winhist = wsu;                           // 64 * 66
    u32* candcnt = wsu + 4224;                    // 64
    u64* cand    = (u64*)(wsu + 8192);            // 64 * 8192 u64 (4 MB)
    u64* rowsel  = (u64*)(wsu + 8192u + 64u * 8192u * 2u);   // 64 u64

    u32 mk0, mk1, nk0, nk1;
    tf2x32(0u, 42u, 0u, 0u, mk0, mk1);            // k_mask  = threefry(42, ctr=(0,0))
    tf2x32(0u, 42u, 0u, 1u, nk0, nk1);            // k_noise = threefry(42, ctr=(0,1))

    hipMemsetAsync(wsu, 0, (4224u + 64u) * sizeof(u32), stream);
    kA_hist<<<1024, 256, 0, stream>>>(mk0, mk1, winhist, candcnt, cand);
    kB_select<<<64, 256, 0, stream>>>(mk0, mk1, winhist, candcnt, cand, rowsel);
    kC_fused<<<16384, 256, 0, stream>>>((const float4*)x, (float4*)xout,
                                        (float4*)maskout, rowsel, mk0, mk1, nk0, nk1);
    (void)ws_size; (void)in_sizes; (void)n_in; (void)out_size;
}